// Round 3
// baseline (883.953 us; speedup 1.0000x reference)
//
#include <hip/hip_runtime.h>
#include <hip/hip_bf16.h>
#include <stdint.h>

#define NEXP 8
#define NROWS 8192
#define HID 2048
#define INTERN 2048
#define CAP 8192
#define KDIM 2048

typedef __attribute__((ext_vector_type(4))) float f32x4;
typedef __attribute__((ext_vector_type(8))) short bf16x8;

__device__ __forceinline__ unsigned short f2bf(float f) {
  union { float f; uint32_t u; } v; v.f = f;
  uint32_t u = v.u;
  uint32_t r = (u + 0x7fffu + ((u >> 16) & 1u)) >> 16;
  return (unsigned short)r;
}
__device__ __forceinline__ float bf2f(unsigned short u) {
  union { uint32_t u; float f; } v; v.u = (uint32_t)u << 16; return v.f;
}
__device__ __forceinline__ void gload16(const unsigned short* g, char* l) {
  __builtin_amdgcn_global_load_lds((const __attribute__((address_space(1))) void*)g,
                                   (__attribute__((address_space(3))) void*)l,
                                   16, 0, 0);
}

// ---------------- x fp32 -> bf16 ----------------
__global__ __launch_bounds__(256) void xcast_kernel(const float* __restrict__ x,
                                                    unsigned short* __restrict__ xb) {
  size_t i = ((size_t)blockIdx.x * 256 + threadIdx.x) * 8;
  size_t stride = (size_t)gridDim.x * 256 * 8;
  const size_t tot = (size_t)NROWS * HID;
  for (; i < tot; i += stride) {
    float4 a = *reinterpret_cast<const float4*>(x + i);
    float4 b = *reinterpret_cast<const float4*>(x + i + 4);
    unsigned short u[8];
    u[0] = f2bf(a.x); u[1] = f2bf(a.y); u[2] = f2bf(a.z); u[3] = f2bf(a.w);
    u[4] = f2bf(b.x); u[5] = f2bf(b.y); u[6] = f2bf(b.z); u[7] = f2bf(b.w);
    *reinterpret_cast<int4*>(xb + i) = *reinterpret_cast<const int4*>(u);
  }
}

// ---------------- router: top-2 of 8, renormalize, bucket per expert ----------------
__global__ void router_kernel(const float* __restrict__ probs,
                              int* __restrict__ cnt,
                              int* __restrict__ brow,
                              float* __restrict__ bw) {
  int row = blockIdx.x * blockDim.x + threadIdx.x;
  if (row >= NROWS) return;
  float p[8];
#pragma unroll
  for (int j = 0; j < 8; j++) p[j] = probs[row * 8 + j];
  int i1 = 0; float v1 = p[0];
#pragma unroll
  for (int j = 1; j < 8; j++) if (p[j] > v1) { v1 = p[j]; i1 = j; }
  int i2 = -1; float v2 = -1e30f;
#pragma unroll
  for (int j = 0; j < 8; j++) if (j != i1 && p[j] > v2) { v2 = p[j]; i2 = j; }
  float s = v1 + v2;
  float w1 = v1 / s, w2 = v2 / s;
  int pos1 = atomicAdd(&cnt[i1], 1);
  brow[i1 * CAP + pos1] = row; bw[i1 * CAP + pos1] = w1;
  int pos2 = atomicAdd(&cnt[i2], 1);
  brow[i2 * CAP + pos2] = row; bw[i2 * CAP + pos2] = w2;
}

__global__ void offsets_kernel(const int* __restrict__ cnt, int* __restrict__ ofs) {
  if (threadIdx.x == 0 && blockIdx.x == 0) {
    int a = 0;
    for (int e = 0; e < NEXP; e++) { ofs[e] = a; a += cnt[e]; }
  }
}

// ---------------- transpose+cast: [E][K][N] f32 -> [E][N][K] bf16, 64x64 tiles ----------------
__global__ __launch_bounds__(256) void transpose_cast_kernel(const float* __restrict__ src,
                                                             unsigned short* __restrict__ dst) {
  __shared__ float tile[64][65];
  const int e = blockIdx.z;
  const int k0 = blockIdx.y * 64;
  const int n0 = blockIdx.x * 64;
  const float* s = src + (size_t)e * KDIM * KDIM;
  unsigned short* d = dst + (size_t)e * KDIM * KDIM;
  const int t = threadIdx.x;
  const int rr = t >> 4, cc = (t & 15) * 4;
#pragma unroll
  for (int i = 0; i < 4; i++) {
    float4 v = *reinterpret_cast<const float4*>(s + (size_t)(k0 + rr + i * 16) * KDIM + n0 + cc);
    tile[rr + i * 16][cc + 0] = v.x; tile[rr + i * 16][cc + 1] = v.y;
    tile[rr + i * 16][cc + 2] = v.z; tile[rr + i * 16][cc + 3] = v.w;
  }
  __syncthreads();
  const int n = t >> 2, kk0 = (t & 3) * 16;
  unsigned short u[16];
#pragma unroll
  for (int j = 0; j < 16; j++) u[j] = f2bf(tile[kk0 + j][n]);
  *reinterpret_cast<int4*>(d + (size_t)(n0 + n) * KDIM + k0 + kk0 + 0) = *reinterpret_cast<const int4*>(&u[0]);
  *reinterpret_cast<int4*>(d + (size_t)(n0 + n) * KDIM + k0 + kk0 + 8) = *reinterpret_cast<const int4*>(&u[8]);
}

// ---------------- 256x256 grouped GEMM, BK=32, quad-buffered, counted vmcnt ----------------
// 512 threads = 8 waves (2M x 4N); per-wave output 128x64; LDS 4 bufs x (A 16KB + B 16KB).
// Pipeline: stage K-tile t+3 at iter t; vmcnt(8) at iter end guarantees t+1 landed
// (t+2,t+3 stay in flight across the barrier -- never drain to 0 in the main loop).
// Race-free: buf[(t+3)&3] was last read at iter t-1, whose reads completed before
// the iter-(t-1) barrier; the stage is issued after that barrier.
// LDS swizzle (64B rows): phys_cb = cb ^ (((row>>1)&3)<<4); applied on BOTH sides
// (pre-swizzled global source for global_load_lds + swizzled ds_read offset).
// EPI 0: hbuf = bf16(acc)        (fc1 -> h1)
// EPI 1: hbuf = bf16(silu(h1)*acc)  in-place   (fc3 -> act)
// EPI 2: out[token] += rw * acc  (atomic scatter, fc2)
template <int EPI>
__global__ __launch_bounds__(512, 2)
void gemm256_kernel(const unsigned short* __restrict__ A,
                    const unsigned short* __restrict__ W,
                    const int* __restrict__ cnt, const int* __restrict__ ofs,
                    const int* __restrict__ brow, const float* __restrict__ bw,
                    unsigned short* __restrict__ hbuf,
                    float* __restrict__ out) {
  const int e = blockIdx.z, mt = blockIdx.y, nt = blockIdx.x;
  const int Me = cnt[e];
  if (mt * 256 >= Me) return;
  __shared__ unsigned short lds[65536];   // 4 x (A[256][32] + B[256][32]) bf16 = 128 KiB
  __shared__ int ridx[256];
  __shared__ float rww[256];
  const int t = threadIdx.x, lane = t & 63, w = t >> 6;
  const int oe = ofs[e];
  if (t < 256) {
    int sl = mt * 256 + t;
    int ok = sl < Me;
    ridx[t] = ok ? brow[e * CAP + sl] : 0;
    rww[t] = ok ? bw[e * CAP + sl] : 0.f;
  }
  __syncthreads();

  const int wm = w >> 2, wn = w & 3;
  const int l15 = lane & 15, kq = lane >> 4;

  // ---- staging mapping: dest linear row = i*128 + w*16 + (lane>>2), cb = (lane&3)*16B
  // global k pre-swizzled: kg = ((lane&3) ^ ((lane>>3)&3)) * 8 elems
  const int srow0 = w * 16 + (lane >> 2);
  const int srow1 = 128 + srow0;
  const int kg = ((lane & 3) ^ ((lane >> 3) & 3)) * 8;
  const unsigned short *gA0, *gA1;
  if (EPI == 2) {
    int s0 = mt * 256 + srow0; if (s0 >= Me) s0 = 0;
    int s1 = mt * 256 + srow1; if (s1 >= Me) s1 = 0;
    gA0 = A + (size_t)(oe + s0) * KDIM + kg;
    gA1 = A + (size_t)(oe + s1) * KDIM + kg;
  } else {
    gA0 = A + (size_t)ridx[srow0] * KDIM + kg;
    gA1 = A + (size_t)ridx[srow1] * KDIM + kg;
  }
  const unsigned short* Wb = W + (size_t)e * KDIM * KDIM;
  const unsigned short* gB0 = Wb + (size_t)(nt * 256 + srow0) * KDIM + kg;
  const unsigned short* gB1 = Wb + (size_t)(nt * 256 + srow1) * KDIM + kg;
  char* ldsb = (char*)lds;
  const int wdst = w * 1024;

  // ---- ds_read fragment offsets (swizzled)
  const int swz = ((l15 >> 1) & 3) << 4;
  const int offA0 = (wm * 128 + l15) * 64 + ((kq * 16) ^ swz);
  const int offB0 = 16384 + (wn * 64 + l15) * 64 + ((kq * 16) ^ swz);

  f32x4 acc[8][4] = {};

#define STAGE(B) do {                                     \
    char* dst = ldsb + (B) * 32768 + wdst;                \
    gload16(gA0, dst);                                    \
    gload16(gA1, dst + 8192);                             \
    gload16(gB0, dst + 16384);                            \
    gload16(gB1, dst + 24576);                            \
    gA0 += 32; gA1 += 32; gB0 += 32; gB1 += 32;           \
  } while (0)

#define COMPUTE(B) do {                                                        \
    const char* ab = ldsb + (B) * 32768;                                       \
    bf16x8 bfr[4], afr[8];                                                     \
    _Pragma("unroll") for (int ni = 0; ni < 4; ni++)                           \
      bfr[ni] = *reinterpret_cast<const bf16x8*>(ab + offB0 + ni * 1024);      \
    _Pragma("unroll") for (int mi = 0; mi < 8; mi++)                           \
      afr[mi] = *reinterpret_cast<const bf16x8*>(ab + offA0 + mi * 1024);      \
    __builtin_amdgcn_s_setprio(1);                                             \
    _Pragma("unroll") for (int mi = 0; mi < 8; mi++)                           \
      _Pragma("unroll") for (int ni = 0; ni < 4; ni++)                         \
        acc[mi][ni] = __builtin_amdgcn_mfma_f32_16x16x32_bf16(afr[mi], bfr[ni], acc[mi][ni], 0, 0, 0); \
    __builtin_amdgcn_s_setprio(0);                                             \
  } while (0)

  // prologue: stage K-tiles 0,1,2 -> bufs 0,1,2; wait until tile 0 landed
  STAGE(0); STAGE(1); STAGE(2);
  asm volatile("s_waitcnt vmcnt(8)" ::: "memory");
  __builtin_amdgcn_s_barrier();

  // main loop: 64 K-tiles total; last 3 peeled (no stage, decreasing vmcnt)
#pragma unroll 4
  for (int kt = 0; kt < 61; ++kt) {
    STAGE((kt + 3) & 3);
    COMPUTE(kt & 3);
    asm volatile("s_waitcnt vmcnt(8)" ::: "memory");
    __builtin_amdgcn_s_barrier();
  }
  COMPUTE(1);
  asm volatile("s_waitcnt vmcnt(4)" ::: "memory");
  __builtin_amdgcn_s_barrier();
  COMPUTE(2);
  asm volatile("s_waitcnt vmcnt(0)" ::: "memory");
  __builtin_amdgcn_s_barrier();
  COMPUTE(3);
#undef STAGE
#undef COMPUTE

  const int mrem = Me - mt * 256;
#pragma unroll
  for (int mi = 0; mi < 8; mi++) {
#pragma unroll
    for (int ni = 0; ni < 4; ni++) {
      const int coln = nt * 256 + wn * 64 + ni * 16 + l15;
#pragma unroll
      for (int r = 0; r < 4; r++) {
        const int lrow = wm * 128 + mi * 16 + kq * 4 + r;
        if (lrow < mrem) {
          if (EPI == 0) {
            hbuf[(size_t)(oe + mt * 256 + lrow) * KDIM + coln] = f2bf(acc[mi][ni][r]);
          } else if (EPI == 1) {
            size_t idx = (size_t)(oe + mt * 256 + lrow) * KDIM + coln;
            float h1 = bf2f(hbuf[idx]);
            float sig = 1.f / (1.f + __expf(-h1));
            hbuf[idx] = f2bf(h1 * sig * acc[mi][ni][r]);
          } else {
            float v = acc[mi][ni][r] * rww[lrow];
            unsafeAtomicAdd(&out[(size_t)ridx[lrow] * HID + coln], v);
          }
        }
      }
    }
  }
}

extern "C" void kernel_launch(void* const* d_in, const int* in_sizes, int n_in,
                              void* d_out, int out_size, void* d_ws, size_t ws_size,
                              hipStream_t stream) {
  const float* x     = (const float*)d_in[0];
  const float* probs = (const float*)d_in[1];
  const float* fc1   = (const float*)d_in[2];
  const float* fc2   = (const float*)d_in[3];
  const float* fc3   = (const float*)d_in[4];
  float* out = (float*)d_out;

  char* ws = (char*)d_ws;
  const size_t WSZ = (size_t)NEXP * HID * INTERN * 2;  // 64 MiB per weight tensor
  unsigned short* wt1 = (unsigned short*)(ws);
  unsigned short* wt3 = (unsigned short*)(ws + WSZ);
  unsigned short* wt2 = (unsigned short*)(ws + 2 * WSZ);
  unsigned short* h1  = (unsigned short*)(ws + 3 * WSZ);            // 16384 x 2048 bf16 (h1, then act)
  unsigned short* xb  = (unsigned short*)(ws + 4 * WSZ);            // 8192 x 2048 bf16 (32 MiB)
  char* rbase = ws + 4 * WSZ + (size_t)NROWS * HID * 2;
  int*   brow = (int*)  (rbase);
  float* bw   = (float*)(rbase + (size_t)NEXP * CAP * 4);
  int*   cnt  = (int*)  (rbase + 2 * (size_t)NEXP * CAP * 4);
  int*   ofs  = (int*)  (rbase + 2 * (size_t)NEXP * CAP * 4 + 64);

  hipMemsetAsync(d_out, 0, (size_t)out_size * sizeof(float), stream);
  hipMemsetAsync(cnt, 0, 64, stream);

  xcast_kernel<<<2048, 256, 0, stream>>>(x, xb);
  transpose_cast_kernel<<<dim3(32, 32, 8), 256, 0, stream>>>(fc1, wt1);
  transpose_cast_kernel<<<dim3(32, 32, 8), 256, 0, stream>>>(fc3, wt3);
  transpose_cast_kernel<<<dim3(32, 32, 8), 256, 0, stream>>>(fc2, wt2);
  router_kernel<<<NROWS / 256, 256, 0, stream>>>(probs, cnt, brow, bw);
  offsets_kernel<<<1, 64, 0, stream>>>(cnt, ofs);

  gemm256_kernel<0><<<dim3(INTERN / 256, CAP / 256, NEXP), 512, 0, stream>>>(xb, wt1, cnt, ofs, brow, bw, h1, out);
  gemm256_kernel<1><<<dim3(INTERN / 256, CAP / 256, NEXP), 512, 0, stream>>>(xb, wt3, cnt, ofs, brow, bw, h1, out);
  gemm256_kernel<2><<<dim3(HID / 256, CAP / 256, NEXP), 512, 0, stream>>>(h1, wt2, cnt, ofs, brow, bw, h1, out);
}